// Round 16
// baseline (49.494 us; speedup 1.0000x reference)
//
#include <hip/hip_runtime.h>
#include <hip/hip_bf16.h>

// SupConLoss forward. Round 16: occupancy push on gram.
//  - __launch_bounds__(256,3): empirical VGPR cap = 256/arg = 85 -> 6 waves/SIMD
//    = 24 waves/CU (was 16). To fit: interleaved B-load->MFMA (bfr 4-8 regs, not
//    16) + fully hoisted t-invariant addressing (src induction pointers, XOR
//    buffer toggles, ds_read column offset as compile-time immediate).
//  - CHUNK=256, TILE=32 (LDS 16KB/block), grid 64x32=2048 = 8 blocks/CU issued,
//    6 resident by VGPR. Total staging traffic unchanged (128 MB L2).
//  - prep/msum/final = round 15 (proven); NCH now 32.
//  - P_i = f_i . m_{lab_i} - 1 exact in f32; gram computes S only; diagonal
//    subtracted analytically (SELF_EXP); slim raw-v_exp_f32 epilogue.
constexpr int B_SZ  = 4096;
constexpr int N_SZ  = 8192;          // B*V
constexpr int CHUNK = 256;           // cols per block
constexpr int TILE  = 32;            // cols per LDS stage
constexpr int NT    = CHUNK / TILE;  // 8
constexpr int NCH   = N_SZ / CHUNK;  // 32
constexpr int BROWS = 128;           // rows per block (4 waves x 32)

typedef __attribute__((ext_vector_type(8))) __bf16 bf16x8;
typedef __attribute__((ext_vector_type(4))) float f32x4;

#define SQRT_CSC  2.1929404f         // sqrt(1/(0.3*ln2)); (c*a).(c*b) = dot/(T*ln2)
#define SELF_EXP  28.0316248f        // exp2(CSC) = e^{1/0.3}: analytic diagonal term
#define NEG_RATIO (-(0.3f / 0.07f))

__device__ __forceinline__ unsigned short f2bf(float f) {
    unsigned u = __float_as_uint(f);
    u += 0x7FFFu + ((u >> 16) & 1u);
    return (unsigned short)(u >> 16);
}

__device__ __forceinline__ void gl_lds16(const unsigned short* g, unsigned short* l) {
    __builtin_amdgcn_global_load_lds(
        (const __attribute__((address_space(1))) unsigned int*)g,
        (__attribute__((address_space(3))) unsigned int*)l, 16, 0, 0);
}

// feat [B,V,128] f32 -> A [N,128] bf16 scaled by sqrt(CSC); zero out[0].
__global__ __launch_bounds__(256) void prep_kernel(const float* __restrict__ feat,
                                                   unsigned short* __restrict__ A,
                                                   float* __restrict__ out) {
    const int tid = threadIdx.x;
    if (blockIdx.x == 0 && tid == 0) out[0] = 0.f;
    int t = blockIdx.x * 256 + tid;            // 0 .. 262143
    int n = t >> 5;
    int q = (t & 31) << 2;
    int b = n & (B_SZ - 1);
    int v = n >> 12;
    const float4 f = *reinterpret_cast<const float4*>(feat + (((size_t)b * 2 + v) << 7) + q);
    ushort4 o;
    o.x = f2bf(f.x * SQRT_CSC); o.y = f2bf(f.y * SQRT_CSC);
    o.z = f2bf(f.z * SQRT_CSC); o.w = f2bf(f.w * SQRT_CSC);
    *reinterpret_cast<ushort4*>(A + (((size_t)n) << 7) + q) = o;
}

// 256 blocks x 16 batch items: per-class per-d partial sums -> mpart[(c*128+d)*256+blk].
__global__ __launch_bounds__(256) void msum_kernel(const float* __restrict__ feat,
                                                   const int* __restrict__ labels,
                                                   float* __restrict__ mpart) {
    __shared__ float sm[2][256];
    const int tid = threadIdx.x;
    const int v = tid >> 7, d = tid & 127;
    const int b0 = blockIdx.x * 16;
    float a0 = 0.f, a1 = 0.f;
#pragma unroll
    for (int it = 0; it < 16; ++it) {
        const int b = b0 + it;
        const float x = feat[(((size_t)b * 2 + v) << 7) + d];
        if (labels[b]) a1 += x; else a0 += x;
    }
    sm[0][tid] = a0; sm[1][tid] = a1;
    __syncthreads();
    if (tid < 128)
        mpart[(size_t)tid * 256 + blockIdx.x] = sm[0][tid] + sm[0][tid + 128];
    else
        mpart[(size_t)tid * 256 + blockIdx.x] = sm[1][tid - 128] + sm[1][tid];
}

// Block: 4 waves x 32 rows = 128 rows, one 256-col chunk, LDS-staged 32-col tiles.
__global__ __launch_bounds__(256, 3) void gram_kernel(const unsigned short* __restrict__ A,
                                                      float* __restrict__ S_part) {
    __shared__ __align__(16) unsigned short tb[2][TILE * 128];  // 2 x 8 KB

    const int tid  = threadIdx.x;
    const int wave = tid >> 6;
    const int lane = tid & 63;
    const int grp  = lane >> 4;
    const int lc   = lane & 15;
    const int row0 = blockIdx.x * BROWS + wave * 32;
    const int col0 = blockIdx.y * CHUNK;

    // A fragments: 2 row-tiles x 4 k-groups (frag g covers k = 32g + 8*grp + [0..8))
    bf16x8 a[2][4];
#pragma unroll
    for (int rt = 0; rt < 2; ++rt) {
        const unsigned short* ap = A + ((size_t)(row0 + 16 * rt + lc) << 7) + grp * 8;
#pragma unroll
        for (int g = 0; g < 4; ++g)
            a[rt][g] = *reinterpret_cast<const bf16x8*>(ap + g * 32);
    }

    // hoisted swizzled LDS read bases (bytes): tc*256 + ((4g+grp)^(tc&7))<<4,
    // tc = 16ct + lc -> tc&7 == lc&7 (ct-invariant); ct term is the offset imm.
    const char* tb0 = (const char*)&tb[0][0];
    const char* bq[4];
#pragma unroll
    for (int g = 0; g < 4; ++g)
        bq[g] = tb0 + lc * 256 + ((((4 * g + grp) ^ (lc & 7))) << 4);

    // hoisted stage addressing: thread stages slots s0=tid, s1=tid+256 (of 512).
    // col r = s>>4, granule c = s&15, source granule = c ^ (r&7)  [t-invariant]
    const int s1 = tid + 256;
    const int r0s = tid >> 4,  c0s = tid & 15;
    const int r1s = s1 >> 4,   c1s = s1 & 15;
    const unsigned short* src0 = A + ((size_t)(col0 + r0s) << 7) + ((c0s ^ (r0s & 7)) << 3);
    const unsigned short* src1 = A + ((size_t)(col0 + r1s) << 7) + ((c1s ^ (r1s & 7)) << 3);
    unsigned short* d0 = &tb[0][0] + tid * 8;   // byte offsets: tid*16, +4096 for s1
    unsigned short* d1 = d0 + 2048;             // (tid+256)*8 shorts = tid*16+4096 B

    float s_acc[2][4] = {{0,0,0,0},{0,0,0,0}};

    // prologue: stage tile 0 into buf 0
    gl_lds16(src0, d0);
    gl_lds16(src1, d1);
    src0 += TILE * 128; src1 += TILE * 128;
    __syncthreads();

    int ro = 0;          // read buffer byte offset (0 / 8192)
    int so = 8192;       // stage buffer byte offset (8192 / 0)

#pragma clang loop unroll(disable)
    for (int t = 0; t < NT; ++t) {
        if (t + 1 < NT) {
            gl_lds16(src0, (unsigned short*)((char*)d0 + so));
            gl_lds16(src1, (unsigned short*)((char*)d1 + so));
            src0 += TILE * 128; src1 += TILE * 128;
        }

#pragma unroll
        for (int ct = 0; ct < 2; ++ct) {
            f32x4 acc0 = {0,0,0,0}, acc1 = {0,0,0,0};
#pragma unroll
            for (int g = 0; g < 4; ++g) {
                const bf16x8 bfr = *reinterpret_cast<const bf16x8*>(bq[g] + ro + ct * 4096);
                acc0 = __builtin_amdgcn_mfma_f32_16x16x32_bf16(a[0][g], bfr, acc0, 0, 0, 0);
                acc1 = __builtin_amdgcn_mfma_f32_16x16x32_bf16(a[1][g], bfr, acc1, 0, 0, 0);
            }
            // slim epilogue: raw v_exp_f32; diagonal subtracted analytically in final
#pragma unroll
            for (int r = 0; r < 4; ++r) {
                s_acc[0][r] += __builtin_amdgcn_exp2f(acc0[r]);
                s_acc[1][r] += __builtin_amdgcn_exp2f(acc1[r]);
            }
        }
        __syncthreads();
        ro ^= 8192; so ^= 8192;
    }

    // reduce across the 16 column-lanes of each k-group
#pragma unroll
    for (int m = 1; m < 16; m <<= 1)
#pragma unroll
        for (int rt = 0; rt < 2; ++rt)
#pragma unroll
            for (int r = 0; r < 4; ++r)
                s_acc[rt][r] += __shfl_xor(s_acc[rt][r], m);

    if (lc == 0) {
        const size_t base = (size_t)blockIdx.y * N_SZ;
#pragma unroll
        for (int rt = 0; rt < 2; ++rt)
#pragma unroll
            for (int r = 0; r < 4; ++r)
                S_part[base + row0 + 16 * rt + 4 * grp + r] = s_acc[rt][r];
    }
}

// Grid 32 x 256: fused mreduce (row-contiguous mpart reads) + label count, combine
// 32 S-partials/row minus analytic self-term, P via f32 dot with class mean, loss.
__global__ __launch_bounds__(256) void final_kernel(const float* __restrict__ S_part,
                                                    const float* __restrict__ feat,
                                                    const int* __restrict__ labels,
                                                    const float* __restrict__ mpart,
                                                    float* __restrict__ out) {
    __shared__ float mv[256];
    __shared__ float red[4];
    __shared__ int   redi[4];
    const int tid = threadIdx.x;

    // mv[tid] = sum over the 256 msum-block partials of (class,d) slot tid
    {
        const float* p = mpart + (size_t)tid * 256;
        float s = 0.f;
#pragma unroll 8
        for (int k = 0; k < 256; k += 4) {
            const float4 x = *reinterpret_cast<const float4*>(p + k);
            s += x.x + x.y + x.z + x.w;
        }
        mv[tid] = s;
    }

    // label count
    int c = 0;
    for (int i = tid; i < B_SZ; i += 256) c += labels[i];
#pragma unroll
    for (int m = 1; m < 64; m <<= 1) c += __shfl_xor(c, m);
    if ((tid & 63) == 0) redi[tid >> 6] = c;
    __syncthreads();                 // also publishes mv[]
    const int c1 = redi[0] + redi[1] + redi[2] + redi[3];

    const int i = blockIdx.x * 256 + tid;
    float S = -SELF_EXP;
#pragma unroll
    for (int k = 0; k < NCH; ++k) S += S_part[(size_t)k * N_SZ + i];

    const int b = i & (B_SZ - 1), v = i >> 12;
    const int lab = labels[b];
    const float* fr = feat + (((size_t)b * 2 + v) << 7);
    const float* mvp = &mv[lab ? 128 : 0];
    float dot = 0.f;
#pragma unroll 8
    for (int d = 0; d < 128; d += 4) {
        const float4 x = *reinterpret_cast<const float4*>(fr + d);
        dot += x.x * mvp[d] + x.y * mvp[d + 1] + x.z * mvp[d + 2] + x.w * mvp[d + 3];
    }

    const int cs = lab ? c1 : (B_SZ - c1);
    const float n = (float)(2 * cs - 1);
    float term = ((dot - 1.0f) * (1.0f / 0.3f) - n * logf(S + 1e-8f)) / (n + 1e-8f);

#pragma unroll
    for (int m = 1; m < 64; m <<= 1) term += __shfl_xor(term, m);
    if ((tid & 63) == 0) red[tid >> 6] = term;
    __syncthreads();
    if (tid == 0)
        atomicAdd(out, (red[0] + red[1] + red[2] + red[3]) * (NEG_RATIO / (float)N_SZ));
}

extern "C" void kernel_launch(void* const* d_in, const int* in_sizes, int n_in,
                              void* d_out, int out_size, void* d_ws, size_t ws_size,
                              hipStream_t stream) {
    const float* feat = (const float*)d_in[0];
    const int* labels = (const int*)d_in[1];
    float* out = (float*)d_out;

    char* ws = (char*)d_ws;
    unsigned short* A = (unsigned short*)ws;                             // 2 MB
    float* S_part = (float*)(ws + (size_t)2 * 1024 * 1024);              // 1 MB (32 x 8192)
    float* mpart  = (float*)(ws + (size_t)3 * 1024 * 1024);              // 256 KB

    prep_kernel<<<dim3(1024), dim3(256), 0, stream>>>(feat, A, out);
    msum_kernel<<<dim3(256), dim3(256), 0, stream>>>(feat, labels, mpart);
    gram_kernel<<<dim3(N_SZ / BROWS, NCH), dim3(256), 0, stream>>>(A, S_part);
    final_kernel<<<dim3(N_SZ / 256), dim3(256), 0, stream>>>(S_part, feat, labels, mpart, out);
}

// Round 17
// 46.616 us; speedup vs baseline: 1.0617x; 1.0617x over previous
//
#include <hip/hip_runtime.h>
#include <hip/hip_bf16.h>

// SupConLoss forward. Round 17: T3/T4-correct pipeline on the round-15 skeleton.
//  - gram: 4-deep LDS ring (4 x 8KB tiles), depth-2 prefetch, counted vmcnt(4),
//    ONE raw s_barrier per epoch (no vmcnt(0)/lgkmcnt(0) drain). Ring depth 4 =>
//    stage target was last read 2 epochs ago; the per-epoch barrier chain makes
//    that write-after-read safe with a single barrier (r10's racy variant needed 2).
//  - wraparound stage keeps vmcnt counting uniform (2 redundant stages/block).
//  - epilogue/addressing identical to r15: slim raw v_exp_f32, diagonal subtracted
//    analytically in final, hoisted ct-invariant swizzled offsets, rolled loop.
//  - prep/msum/final byte-identical to round 15 (best, 47.4us).
constexpr int B_SZ  = 4096;
constexpr int N_SZ  = 8192;          // B*V
constexpr int CHUNK = 512;           // cols per block
constexpr int TILE  = 32;            // cols per ring slot (8 KB)
constexpr int NT    = CHUNK / TILE;  // 16
constexpr int NCH   = N_SZ / CHUNK;  // 16
constexpr int BROWS = 128;           // rows per block (4 waves x 32)

typedef __attribute__((ext_vector_type(8))) __bf16 bf16x8;
typedef __attribute__((ext_vector_type(4))) float f32x4;

#define SQRT_CSC  2.1929404f         // sqrt(1/(0.3*ln2)); (c*a).(c*b) = dot/(T*ln2)
#define SELF_EXP  28.0316248f        // exp2(CSC) = e^{1/0.3}: analytic diagonal term
#define NEG_RATIO (-(0.3f / 0.07f))

__device__ __forceinline__ unsigned short f2bf(float f) {
    unsigned u = __float_as_uint(f);
    u += 0x7FFFu + ((u >> 16) & 1u);
    return (unsigned short)(u >> 16);
}

__device__ __forceinline__ void gl_lds16(const unsigned short* g, unsigned short* l) {
    __builtin_amdgcn_global_load_lds(
        (const __attribute__((address_space(1))) unsigned int*)g,
        (__attribute__((address_space(3))) unsigned int*)l, 16, 0, 0);
}

// feat [B,V,128] f32 -> A [N,128] bf16 scaled by sqrt(CSC); zero out[0].
__global__ __launch_bounds__(256) void prep_kernel(const float* __restrict__ feat,
                                                   unsigned short* __restrict__ A,
                                                   float* __restrict__ out) {
    const int tid = threadIdx.x;
    if (blockIdx.x == 0 && tid == 0) out[0] = 0.f;
    int t = blockIdx.x * 256 + tid;            // 0 .. 262143
    int n = t >> 5;
    int q = (t & 31) << 2;
    int b = n & (B_SZ - 1);
    int v = n >> 12;
    const float4 f = *reinterpret_cast<const float4*>(feat + (((size_t)b * 2 + v) << 7) + q);
    ushort4 o;
    o.x = f2bf(f.x * SQRT_CSC); o.y = f2bf(f.y * SQRT_CSC);
    o.z = f2bf(f.z * SQRT_CSC); o.w = f2bf(f.w * SQRT_CSC);
    *reinterpret_cast<ushort4*>(A + (((size_t)n) << 7) + q) = o;
}

// 256 blocks x 16 batch items: per-class per-d partial sums -> mpart[(c*128+d)*256+blk].
__global__ __launch_bounds__(256) void msum_kernel(const float* __restrict__ feat,
                                                   const int* __restrict__ labels,
                                                   float* __restrict__ mpart) {
    __shared__ float sm[2][256];
    const int tid = threadIdx.x;
    const int v = tid >> 7, d = tid & 127;
    const int b0 = blockIdx.x * 16;
    float a0 = 0.f, a1 = 0.f;
#pragma unroll
    for (int it = 0; it < 16; ++it) {
        const int b = b0 + it;
        const float x = feat[(((size_t)b * 2 + v) << 7) + d];
        if (labels[b]) a1 += x; else a0 += x;
    }
    sm[0][tid] = a0; sm[1][tid] = a1;
    __syncthreads();
    if (tid < 128)
        mpart[(size_t)tid * 256 + blockIdx.x] = sm[0][tid] + sm[0][tid + 128];
    else
        mpart[(size_t)tid * 256 + blockIdx.x] = sm[1][tid - 128] + sm[1][tid];
}

// Block: 4 waves x 32 rows = 128 rows, one 512-col chunk; 4-deep ring of 32-col tiles.
__global__ __launch_bounds__(256, 2) void gram_kernel(const unsigned short* __restrict__ A,
                                                      float* __restrict__ S_part) {
    __shared__ __align__(16) unsigned short tb[4][TILE * 128];  // 4 x 8 KB ring

    const int tid  = threadIdx.x;
    const int wave = tid >> 6;
    const int lane = tid & 63;
    const int grp  = lane >> 4;
    const int lc   = lane & 15;
    const int row0 = blockIdx.x * BROWS + wave * 32;
    const int col0 = blockIdx.y * CHUNK;

    // A fragments: 2 row-tiles x 4 k-groups (frag g covers k = 32g + 8*grp + [0..8))
    bf16x8 a[2][4];
#pragma unroll
    for (int rt = 0; rt < 2; ++rt) {
        const unsigned short* ap = A + ((size_t)(row0 + 16 * rt + lc) << 7) + grp * 8;
#pragma unroll
        for (int g = 0; g < 4; ++g)
            a[rt][g] = *reinterpret_cast<const bf16x8*>(ap + g * 32);
    }

    // ct-invariant swizzled read offsets (elements): tc=16ct+lc, tc&7==lc&7;
    // ct contributes 16*128=2048 elements (compile-time immediate in the loop).
    int off[4];
#pragma unroll
    for (int g = 0; g < 4; ++g)
        off[g] = lc * 128 + (((4 * g + grp) ^ (lc & 7)) << 3);

    float s_acc[2][4] = {{0,0,0,0},{0,0,0,0}};

    // stage tile tt (mod NT) into ring slot tt&3: 512 16B-slots, 2 per thread.
    // LDS slot (r,c) holds global 16B-granule (c ^ (r&7)) of tile-row r.
    auto stage = [&](int tt) {
        const unsigned short* gbase = A + ((size_t)(col0 + (tt & (NT - 1)) * TILE) << 7);
        unsigned short* dst = &tb[tt & 3][0];
#pragma unroll
        for (int k = 0; k < 2; ++k) {
            const int s = tid + 256 * k;           // 0..511
            const int r = s >> 4, c = s & 15;
            const int src = (r << 4) + (c ^ (r & 7));
            gl_lds16(gbase + src * 8, dst + s * 8);
        }
    };

    stage(0);
    stage(1);                                      // depth-2 prologue (4 wave-loads in flight)

#pragma clang loop unroll(disable)
    for (int t = 0; t < NT; ++t) {
        stage(t + 2);                              // issue 2 loads (6 in flight)
        asm volatile("s_waitcnt vmcnt(4)" ::: "memory");   // my tile-t loads landed
        __builtin_amdgcn_s_barrier();                      // everyone's tile-t landed;
                                                           // also WAR-safe: slot (t+2)&3
                                                           // was read at t-2, before
                                                           // barrier(t-1) < this issue.

        const unsigned short* bp = &tb[t & 3][0];
#pragma unroll
        for (int ct = 0; ct < 2; ++ct) {
            bf16x8 bfr[4];
#pragma unroll
            for (int g = 0; g < 4; ++g)
                bfr[g] = *reinterpret_cast<const bf16x8*>(bp + ct * 2048 + off[g]);

            f32x4 acc0 = {0,0,0,0}, acc1 = {0,0,0,0};
#pragma unroll
            for (int g = 0; g < 4; ++g) {
                acc0 = __builtin_amdgcn_mfma_f32_16x16x32_bf16(a[0][g], bfr[g], acc0, 0, 0, 0);
                acc1 = __builtin_amdgcn_mfma_f32_16x16x32_bf16(a[1][g], bfr[g], acc1, 0, 0, 0);
            }
            // slim epilogue: raw v_exp_f32; diagonal subtracted analytically in final
#pragma unroll
            for (int r = 0; r < 4; ++r) {
                s_acc[0][r] += __builtin_amdgcn_exp2f(acc0[r]);
                s_acc[1][r] += __builtin_amdgcn_exp2f(acc1[r]);
            }
        }
    }

    // reduce across the 16 column-lanes of each k-group
#pragma unroll
    for (int m = 1; m < 16; m <<= 1)
#pragma unroll
        for (int rt = 0; rt < 2; ++rt)
#pragma unroll
            for (int r = 0; r < 4; ++r)
                s_acc[rt][r] += __shfl_xor(s_acc[rt][r], m);

    if (lc == 0) {
        const size_t base = (size_t)blockIdx.y * N_SZ;
#pragma unroll
        for (int rt = 0; rt < 2; ++rt)
#pragma unroll
            for (int r = 0; r < 4; ++r)
                S_part[base + row0 + 16 * rt + 4 * grp + r] = s_acc[rt][r];
    }
}

// Grid 32 x 256: fused mreduce (row-contiguous mpart reads) + label count, combine
// 16 S-partials/row minus analytic self-term, P via f32 dot with class mean, loss.
__global__ __launch_bounds__(256) void final_kernel(const float* __restrict__ S_part,
                                                    const float* __restrict__ feat,
                                                    const int* __restrict__ labels,
                                                    const float* __restrict__ mpart,
                                                    float* __restrict__ out) {
    __shared__ float mv[256];
    __shared__ float red[4];
    __shared__ int   redi[4];
    const int tid = threadIdx.x;

    // mv[tid] = sum over the 256 msum-block partials of (class,d) slot tid
    {
        const float* p = mpart + (size_t)tid * 256;
        float s = 0.f;
#pragma unroll 8
        for (int k = 0; k < 256; k += 4) {
            const float4 x = *reinterpret_cast<const float4*>(p + k);
            s += x.x + x.y + x.z + x.w;
        }
        mv[tid] = s;
    }

    // label count
    int c = 0;
    for (int i = tid; i < B_SZ; i += 256) c += labels[i];
#pragma unroll
    for (int m = 1; m < 64; m <<= 1) c += __shfl_xor(c, m);
    if ((tid & 63) == 0) redi[tid >> 6] = c;
    __syncthreads();                 // also publishes mv[]
    const int c1 = redi[0] + redi[1] + redi[2] + redi[3];

    const int i = blockIdx.x * 256 + tid;
    float S = -SELF_EXP;
#pragma unroll
    for (int k = 0; k < NCH; ++k) S += S_part[(size_t)k * N_SZ + i];

    const int b = i & (B_SZ - 1), v = i >> 12;
    const int lab = labels[b];
    const float* fr = feat + (((size_t)b * 2 + v) << 7);
    const float* mvp = &mv[lab ? 128 : 0];
    float dot = 0.f;
#pragma unroll 8
    for (int d = 0; d < 128; d += 4) {
        const float4 x = *reinterpret_cast<const float4*>(fr + d);
        dot += x.x * mvp[d] + x.y * mvp[d + 1] + x.z * mvp[d + 2] + x.w * mvp[d + 3];
    }

    const int cs = lab ? c1 : (B_SZ - c1);
    const float n = (float)(2 * cs - 1);
    float term = ((dot - 1.0f) * (1.0f / 0.3f) - n * logf(S + 1e-8f)) / (n + 1e-8f);

#pragma unroll
    for (int m = 1; m < 64; m <<= 1) term += __shfl_xor(term, m);
    if ((tid & 63) == 0) red[tid >> 6] = term;
    __syncthreads();
    if (tid == 0)
        atomicAdd(out, (red[0] + red[1] + red[2] + red[3]) * (NEG_RATIO / (float)N_SZ));
}

extern "C" void kernel_launch(void* const* d_in, const int* in_sizes, int n_in,
                              void* d_out, int out_size, void* d_ws, size_t ws_size,
                              hipStream_t stream) {
    const float* feat = (const float*)d_in[0];
    const int* labels = (const int*)d_in[1];
    float* out = (float*)d_out;

    char* ws = (char*)d_ws;
    unsigned short* A = (unsigned short*)ws;                             // 2 MB
    float* S_part = (float*)(ws + (size_t)2 * 1024 * 1024);              // 512 KB
    float* mpart  = (float*)(ws + (size_t)2 * 1024 * 1024 + 512 * 1024); // 256 KB

    prep_kernel<<<dim3(1024), dim3(256), 0, stream>>>(feat, A, out);
    msum_kernel<<<dim3(256), dim3(256), 0, stream>>>(feat, labels, mpart);
    gram_kernel<<<dim3(N_SZ / BROWS, NCH), dim3(256), 0, stream>>>(A, S_part);
    final_kernel<<<dim3(N_SZ / 256), dim3(256), 0, stream>>>(S_part, feat, labels, mpart, out);
}